// Round 6
// baseline (1120.174 us; speedup 1.0000x reference)
//
#include <hip/hip_runtime.h>

// RNN: B=512, T=1024, I=64, H=128, fp32 in/out.
// Round-5 postmortem: cross-wave h sharing forced a per-step __syncthreads;
// per-step time 1219 cyc with LDS pipe 47% / VALU 55% = latency-bound.
// Round 6: WAVE-PER-ROW, ZERO BARRIERS. 512 blocks x 64 threads (1 wave).
//  - Lane L computes h_next[2L], h_next[2L+1] over FULL K (no reduce).
//  - All 192 weight half2 (W_ih 2x32 + W_hh 2x64) in arch VGPRs;
//    __launch_bounds__(64,1) gives the 512-VGPR budget so nothing is
//    AGPR-parked (rounds 2/3 failure mode).
//  - h: wave-private 256 B LDS buffer; write packed half2/lane, read back
//    as 16 same-address ds_read_b128 broadcasts (conflict-free). DS pipe
//    is in-order per wave -> no sync needed, ever.
//  - x: 32-step chunks staged fp32->f16 in LDS, register-prefetched.
// Issue floor: 192 v_dot2 x 2cyc = 384 cyc/step -> ~170-220 us.

#define Bsz 512
#define Tt  1024
#define Ii  64
#define Hh  128
constexpr int TC = 32;          // timesteps per staged x chunk
constexpr int NT = 64;          // ONE wave per block

typedef _Float16 half2v __attribute__((ext_vector_type(2)));
typedef _Float16 half4v __attribute__((ext_vector_type(4)));
typedef _Float16 half8v __attribute__((ext_vector_type(8)));

union h8u { half8v v; half2v h[4]; };   // subregister aliasing

__device__ __forceinline__ float dot2(half2v a, half2v b, float c) {
#if __has_builtin(__builtin_amdgcn_fdot2)
    return __builtin_amdgcn_fdot2(a, b, c, false);
#else
    return c + (float)a[0] * (float)b[0] + (float)a[1] * (float)b[1];
#endif
}

__device__ __forceinline__ float fast_tanh(float x) {
    float t = __builtin_amdgcn_exp2f(x * 2.8853900817779268f);
    return 1.0f - 2.0f * __builtin_amdgcn_rcpf(t + 1.0f);
}
__device__ __forceinline__ float fast_sigmoid(float z) {
    float t = __builtin_amdgcn_exp2f(-z * 1.4426950408889634f);
    return __builtin_amdgcn_rcpf(1.0f + t);
}
__device__ __forceinline__ half4v cvt4(float4 p) {
    half4v r; r[0] = (_Float16)p.x; r[1] = (_Float16)p.y;
    r[2] = (_Float16)p.z; r[3] = (_Float16)p.w; return r;
}

__global__ __launch_bounds__(NT, 1)   // 1 wave/EU min -> full 512-VGPR budget
void rnn_wave(const float* __restrict__ x,
              const float* __restrict__ W_ih,
              const float* __restrict__ W_hh,
              const float* __restrict__ b_ih,
              const float* __restrict__ b_hh,
              const float* __restrict__ fc_w,
              const float* __restrict__ fc_b,
              float* __restrict__ out)
{
    __shared__ __align__(16) _Float16 xs[2][TC * Ii];  // 2 x 4 KB f16 x chunks
    __shared__ __align__(16) _Float16 hs[Hh];          // 256 B wave-private h

    const int L   = threadIdx.x;       // 0..63
    const int row = blockIdx.x;
    const int j0  = 2 * L, j1 = j0 + 1;

    // ---- weights -> f16 registers: 192 half2 = 192 VGPRs ----
    half2v wih0[Ii / 2], wih1[Ii / 2];     // 32 + 32
    {
        const float* g0 = W_ih + j0 * Ii;
        const float* g1 = W_ih + j1 * Ii;
        #pragma unroll
        for (int k = 0; k < Ii / 2; ++k) {
            wih0[k][0] = (_Float16)g0[2*k]; wih0[k][1] = (_Float16)g0[2*k+1];
            wih1[k][0] = (_Float16)g1[2*k]; wih1[k][1] = (_Float16)g1[2*k+1];
        }
    }
    half2v whh0[Hh / 2], whh1[Hh / 2];     // 64 + 64
    {
        const float* g0 = W_hh + j0 * Hh;
        const float* g1 = W_hh + j1 * Hh;
        #pragma unroll
        for (int k = 0; k < Hh / 2; ++k) {
            whh0[k][0] = (_Float16)g0[2*k]; whh0[k][1] = (_Float16)g0[2*k+1];
            whh1[k][0] = (_Float16)g1[2*k]; whh1[k][1] = (_Float16)g1[2*k+1];
        }
    }
    const float bias0 = b_ih[j0] + b_hh[j0];
    const float bias1 = b_ih[j1] + b_hh[j1];
    const float fw0 = fc_w[j0], fw1 = fc_w[j1];

    ((half2v*)hs)[L] = (half2v)0;          // h0 = 0 (wave-synchronous)

    // ---- x chunk prefetch: 8 float4/lane (32 steps x 64 I, coalesced) ----
    const float4* xsrc = (const float4*)(x + (size_t)row * Tt * Ii);
    float4 p[8];
    #pragma unroll
    for (int i = 0; i < 8; ++i) p[i] = xsrc[L + 64 * i];

    float h0n = 0.0f, h1n = 0.0f;

    for (int t0 = 0; t0 < Tt; t0 += TC) {
        const int cbuf = (t0 / TC) & 1;
        #pragma unroll
        for (int i = 0; i < 8; ++i)
            ((half4v*)xs[cbuf])[L + 64 * i] = cvt4(p[i]);
        if (t0 + TC < Tt) {
            const int base = (t0 + TC) * (Ii / 4);
            #pragma unroll
            for (int i = 0; i < 8; ++i) p[i] = xsrc[base + L + 64 * i];
        }
        // no barrier: single wave, in-order DS pipe

        #pragma unroll 1
        for (int tt = 0; tt < TC; ++tt) {
            const half8v* xv = (const half8v*)(xs[cbuf] + tt * Ii);
            const half8v* hv = (const half8v*)hs;

            float a0 = 0.f, a1 = 0.f, a2 = 0.f, a3 = 0.f;   // j0 chains
            float c0 = 0.f, c1 = 0.f, c2 = 0.f, c3 = 0.f;   // j1 chains

            #pragma unroll
            for (int i = 0; i < 8; ++i) {          // x part: 8 bcast, 64 dot2
                h8u q; q.v = xv[i];
                a0 = dot2(q.h[0], wih0[4*i+0], a0);
                a1 = dot2(q.h[1], wih0[4*i+1], a1);
                a2 = dot2(q.h[2], wih0[4*i+2], a2);
                a3 = dot2(q.h[3], wih0[4*i+3], a3);
                c0 = dot2(q.h[0], wih1[4*i+0], c0);
                c1 = dot2(q.h[1], wih1[4*i+1], c1);
                c2 = dot2(q.h[2], wih1[4*i+2], c2);
                c3 = dot2(q.h[3], wih1[4*i+3], c3);
            }
            #pragma unroll
            for (int i = 0; i < 16; ++i) {         // h part: 16 bcast, 128 dot2
                h8u q; q.v = hv[i];
                a0 = dot2(q.h[0], whh0[4*i+0], a0);
                a1 = dot2(q.h[1], whh0[4*i+1], a1);
                a2 = dot2(q.h[2], whh0[4*i+2], a2);
                a3 = dot2(q.h[3], whh0[4*i+3], a3);
                c0 = dot2(q.h[0], whh1[4*i+0], c0);
                c1 = dot2(q.h[1], whh1[4*i+1], c1);
                c2 = dot2(q.h[2], whh1[4*i+2], c2);
                c3 = dot2(q.h[3], whh1[4*i+3], c3);
            }
            h0n = fast_tanh(((a0 + a1) + (a2 + a3)) + bias0);
            h1n = fast_tanh(((c0 + c1) + (c2 + c3)) + bias1);
            half2v hw; hw[0] = (_Float16)h0n; hw[1] = (_Float16)h1n;
            ((half2v*)hs)[L] = hw;         // in-order DS: next read sees it
        }
    }

    // ---- epilogue: out[row] = sigmoid(fc_b + sum_j fc_w[j] * h[j]) ----
    float partial = fw0 * h0n + fw1 * h1n;
    #pragma unroll
    for (int off = 32; off > 0; off >>= 1)
        partial += __shfl_down(partial, off, 64);
    if (L == 0) out[row] = fast_sigmoid(partial + fc_b[0]);
}

extern "C" void kernel_launch(void* const* d_in, const int* in_sizes, int n_in,
                              void* d_out, int out_size, void* d_ws, size_t ws_size,
                              hipStream_t stream) {
    const float* x    = (const float*)d_in[0];
    const float* W_ih = (const float*)d_in[1];
    const float* W_hh = (const float*)d_in[2];
    const float* b_ih = (const float*)d_in[3];
    const float* b_hh = (const float*)d_in[4];
    const float* fc_w = (const float*)d_in[5];
    const float* fc_b = (const float*)d_in[6];
    float* out = (float*)d_out;

    rnn_wave<<<Bsz, NT, 0, stream>>>(x, W_ih, W_hh, b_ih, b_hh, fc_w, fc_b, out);
}

// Round 7
// 757.048 us; speedup vs baseline: 1.4797x; 1.4797x over previous
//
#include <hip/hip_runtime.h>

// RNN: B=512, T=1024, I=64, H=128, fp32 in/out.
// Best so far (R5): J2xK4 f16 dot2, 520 us, LDS pipe 576 cyc/CU/step vs
// VALU 256 -> neither saturated, ~600 cyc barrier/wait gap.
// Round 7: K-split-8 x J-tile-4. Same 48 half2 weight VGPRs per thread
// (<=50-reg rule: R2/R3/R6 all AGPR-parked bigger arrays), but LDS reads
// per thread per step drop 6 -> 3 ds_read_b128. 512 blocks x 256 thr =
// 8 waves/CU (>=8 rule from R6 postmortem: 1-2 waves/CU exposes latency).
//  - thread (jg = tid>>3, kq = tid&7): 4 j's x K-eighth (8 of I, 16 of H)
//  - butterfly reduce over the 8 kq lanes (xor 1,2,4)
//  - h double-buffered in LDS (one barrier per step); x staged fp32->f16
//    in 32-step double-buffered chunks, register-prefetched.
// Read banks: x b128 -> all 32 banks; h 2x b128 -> 2-way (free, m136).

#define Bsz 512
#define Tt  1024
#define Ii  64
#define Hh  128
constexpr int TC = 32;          // timesteps per LDS chunk
constexpr int NT = 256;         // threads per block (4 waves)

typedef _Float16 half2v __attribute__((ext_vector_type(2)));
typedef _Float16 half4v __attribute__((ext_vector_type(4)));
typedef _Float16 half8v __attribute__((ext_vector_type(8)));

union h8u { half8v v; half2v h[4]; };   // subregister aliasing

__device__ __forceinline__ float dot2(half2v a, half2v b, float c) {
#if __has_builtin(__builtin_amdgcn_fdot2)
    return __builtin_amdgcn_fdot2(a, b, c, false);
#else
    return c + (float)a[0] * (float)b[0] + (float)a[1] * (float)b[1];
#endif
}

__device__ __forceinline__ float fast_tanh(float x) {
    float t = __builtin_amdgcn_exp2f(x * 2.8853900817779268f);
    return 1.0f - 2.0f * __builtin_amdgcn_rcpf(t + 1.0f);
}
__device__ __forceinline__ float fast_sigmoid(float z) {
    float t = __builtin_amdgcn_exp2f(-z * 1.4426950408889634f);
    return __builtin_amdgcn_rcpf(1.0f + t);
}
__device__ __forceinline__ half4v cvt4(float4 p) {
    half4v r; r[0] = (_Float16)p.x; r[1] = (_Float16)p.y;
    r[2] = (_Float16)p.z; r[3] = (_Float16)p.w; return r;
}

__global__ __launch_bounds__(NT, 4)   // 128-VGPR budget; need ~95 -> no parking
void rnn_fused(const float* __restrict__ x,
               const float* __restrict__ W_ih,
               const float* __restrict__ W_hh,
               const float* __restrict__ b_ih,
               const float* __restrict__ b_hh,
               const float* __restrict__ fc_w,
               const float* __restrict__ fc_b,
               float* __restrict__ out)
{
    __shared__ __align__(16) _Float16 xs[2][TC * Ii];  // 2 x 4 KB f16 x chunks
    __shared__ __align__(16) _Float16 hbuf[2][Hh];     // 2 x 256 B f16 hidden
    __shared__ float wred[NT / 64];

    const int tid = threadIdx.x;
    const int kq  = tid & 7;           // K-eighth
    const int jg  = tid >> 3;          // 0..31 hidden-unit quad
    const int row = blockIdx.x;

    // ---- weights -> f16 registers: 48 half2 = 48 VGPRs ----
    half2v wih[16];                    // [j'][i]: W_ih[4jg+j'][kq*8 + 2i..]
    half2v whh[32];                    // [j'][i]: W_hh[4jg+j'][kq*16 + 2i..]
    float  bias[4], fw[4];
    #pragma unroll
    for (int jj = 0; jj < 4; ++jj) {
        const int j = jg * 4 + jj;
        const float* g = W_ih + j * Ii + kq * 8;
        #pragma unroll
        for (int i = 0; i < 4; ++i) {
            wih[jj*4+i][0] = (_Float16)g[2*i];
            wih[jj*4+i][1] = (_Float16)g[2*i+1];
        }
        const float* G = W_hh + j * Hh + kq * 16;
        #pragma unroll
        for (int i = 0; i < 8; ++i) {
            whh[jj*8+i][0] = (_Float16)G[2*i];
            whh[jj*8+i][1] = (_Float16)G[2*i+1];
        }
        bias[jj] = b_ih[j] + b_hh[j];
        fw[jj]   = fc_w[j];
    }

    if (tid < Hh / 2) ((half2v*)hbuf[0])[tid] = (half2v)0;   // h0 = 0

    // ---- x chunk prefetch: 2 float4/thread, stored as f16 ----
    const float4* xsrc = (const float4*)(x + (size_t)row * Tt * Ii);
    float4 p0 = xsrc[tid];
    float4 p1 = xsrc[tid + NT];

    int   cur = 0;
    float h0 = 0.f, h1 = 0.f, h2 = 0.f, h3 = 0.f;

    for (int t0 = 0; t0 < Tt; t0 += TC) {
        const int cbuf = (t0 / TC) & 1;
        ((half4v*)xs[cbuf])[tid]      = cvt4(p0);
        ((half4v*)xs[cbuf])[tid + NT] = cvt4(p1);
        if (t0 + TC < Tt) {
            const int base = (t0 + TC) * (Ii / 4);
            p0 = xsrc[base + tid];
            p1 = xsrc[base + tid + NT];
        }
        __syncthreads();

        #pragma unroll 2
        for (int tt = 0; tt < TC; ++tt) {
            h8u xq, hq0, hq1;                       // 3 ds_read_b128
            xq.v  = *(const half8v*)(xs[cbuf] + tt * Ii + kq * 8);
            hq0.v = *(const half8v*)(hbuf[cur] + kq * 16);
            hq1.v = *(const half8v*)(hbuf[cur] + kq * 16 + 8);

            float a0 = 0.f, a1 = 0.f, a2 = 0.f, a3 = 0.f;   // j'=0..3 chains
            #pragma unroll
            for (int i = 0; i < 4; ++i) {           // x part: 16 dot2
                half2v u = xq.h[i];
                a0 = dot2(u, wih[i],      a0);
                a1 = dot2(u, wih[4 + i],  a1);
                a2 = dot2(u, wih[8 + i],  a2);
                a3 = dot2(u, wih[12 + i], a3);
            }
            #pragma unroll
            for (int i = 0; i < 4; ++i) {           // h part lo: 16 dot2
                half2v u = hq0.h[i];
                a0 = dot2(u, whh[i],      a0);
                a1 = dot2(u, whh[8 + i],  a1);
                a2 = dot2(u, whh[16 + i], a2);
                a3 = dot2(u, whh[24 + i], a3);
            }
            #pragma unroll
            for (int i = 0; i < 4; ++i) {           // h part hi: 16 dot2
                half2v u = hq1.h[i];
                a0 = dot2(u, whh[4 + i],  a0);
                a1 = dot2(u, whh[12 + i], a1);
                a2 = dot2(u, whh[20 + i], a2);
                a3 = dot2(u, whh[28 + i], a3);
            }
            // butterfly over the 8 kq lanes (all lanes end with full sums)
            #pragma unroll
            for (int m = 1; m <= 4; m <<= 1) {
                a0 += __shfl_xor(a0, m, 64);
                a1 += __shfl_xor(a1, m, 64);
                a2 += __shfl_xor(a2, m, 64);
                a3 += __shfl_xor(a3, m, 64);
            }
            h0 = fast_tanh(a0 + bias[0]);
            h1 = fast_tanh(a1 + bias[1]);
            h2 = fast_tanh(a2 + bias[2]);
            h3 = fast_tanh(a3 + bias[3]);
            if (kq == 0) {                          // 1 ds_write_b64
                half4v hw;
                hw[0] = (_Float16)h0; hw[1] = (_Float16)h1;
                hw[2] = (_Float16)h2; hw[3] = (_Float16)h3;
                ((half4v*)hbuf[cur ^ 1])[jg] = hw;
            }
            __syncthreads();
            cur ^= 1;
        }
    }

    // ---- epilogue: out[row] = sigmoid(fc_b + sum_j fc_w[j] * h[j]) ----
    float partial = (kq == 0)
        ? (fw[0] * h0 + fw[1] * h1 + fw[2] * h2 + fw[3] * h3) : 0.0f;
    #pragma unroll
    for (int off = 32; off > 0; off >>= 1)
        partial += __shfl_down(partial, off, 64);
    if ((tid & 63) == 0) wred[tid >> 6] = partial;
    __syncthreads();
    if (tid == 0) {
        float z = fc_b[0];
        #pragma unroll
        for (int w = 0; w < NT / 64; ++w) z += wred[w];
        out[row] = fast_sigmoid(z);
    }
}

extern "C" void kernel_launch(void* const* d_in, const int* in_sizes, int n_in,
                              void* d_out, int out_size, void* d_ws, size_t ws_size,
                              hipStream_t stream) {
    const float* x    = (const float*)d_in[0];
    const float* W_ih = (const float*)d_in[1];
    const float* W_hh = (const float*)d_in[2];
    const float* b_ih = (const float*)d_in[3];
    const float* b_hh = (const float*)d_in[4];
    const float* fc_w = (const float*)d_in[5];
    const float* fc_b = (const float*)d_in[6];
    float* out = (float*)d_out;

    rnn_fused<<<Bsz, NT, 0, stream>>>(x, W_ih, W_hh, b_ih, b_hh, fc_w, fc_b, out);
}